// Round 9
// baseline (3140.899 us; speedup 1.0000x reference)
//
#include <hip/hip_runtime.h>
#include <math.h>

#define S_N 3000
#define NCOLS 30000
#define SCHUNK 16
#define KTILES 938      // ceil(30000/32)
#define TPC 59          // tiles per chunk (16*59 = 944 >= 938)
#define PST 688         // P row stride (pads LDS to 81.8 KB -> 1 block/CU)

typedef __bf16 v8bf __attribute__((ext_vector_type(8)));
typedef float v16f __attribute__((ext_vector_type(16)));

__device__ __forceinline__ float sigm(float x) { return 1.0f / (1.0f + expf(-x)); }

__device__ __forceinline__ bool bet(float av, int ai, float bv, int bi) {
  return (av > bv) || (av == bv && ai < bi);
}

// streaming insert (candidates ascending by index): strict > == lax.top_k tie rule
template <int M>
__device__ __forceinline__ void insS(float (&v)[M], int (&ix)[M], float nv, int ni) {
  if (!(nv > v[M - 1])) return;
  bool b[M];
#pragma unroll
  for (int q = 0; q < M; q++) b[q] = nv > v[q];
#pragma unroll
  for (int q = M - 1; q > 0; q--) {
    v[q]  = b[q] ? (b[q - 1] ? v[q - 1] : nv) : v[q];
    ix[q] = b[q] ? (b[q - 1] ? ix[q - 1] : ni) : ix[q];
  }
  if (b[0]) { v[0] = nv; ix[0] = ni; }
}

// full comparator insert (value desc, index asc) for arbitrary-order merges
template <int M>
__device__ __forceinline__ void insF(float (&v)[M], int (&ix)[M], float nv, int ni) {
  if (!bet(nv, ni, v[M - 1], ix[M - 1])) return;
  bool b[M];
#pragma unroll
  for (int q = 0; q < M; q++) b[q] = bet(nv, ni, v[q], ix[q]);
#pragma unroll
  for (int q = M - 1; q > 0; q--) {
    v[q]  = b[q] ? (b[q - 1] ? v[q - 1] : nv) : v[q];
    ix[q] = b[q] ? (b[q - 1] ? ix[q - 1] : ni) : ix[q];
  }
  if (b[0]) { v[0] = nv; ix[0] = ni; }
}

__device__ __forceinline__ unsigned short f2bf_rne(float f) {
  unsigned int u = __float_as_uint(f);
  unsigned int r = (u + 0x7fffu + ((u >> 16) & 1u)) >> 16;
  return (unsigned short)r;
}
__device__ __forceinline__ float bf2f(unsigned short h) {
  return __uint_as_float(((unsigned int)h) << 16);
}

// ---------------------------------------------------------------------------
// Kernel 1: LSTM. 250 blocks x 512 threads. Thread (kh = tid>>8, g = tid&255)
// owns gates jA=g, jB=g+256 at k-half kh: 128 weight floats register-
// stationary. KEY: LDS is padded past 80 KB so only ONE block fits per CU ->
// the backend's occupancy target becomes 2 waves/EU -> 256-VGPR budget, and
// the 128-float weight array finally stays in VGPRs. (R4/R5: 128-budget ->
// AGPR shuttle, 1 accvgpr_read/FMA; R6: 128-budget + pin -> 2.5 GB scratch
// spill; R8: direct AGPR-source VALU rejected by the gfx950 assembler.)
// ---------------------------------------------------------------------------
__global__ __launch_bounds__(512, 2) void lstm_kernel(
    const float* __restrict__ Xs, const float* __restrict__ Wih,
    const float* __restrict__ Whh, const float* __restrict__ bih,
    const float* __restrict__ bhh, float* __restrict__ H10)
{
  __shared__ float h_s[12 * 128];      // 6 KB
  __shared__ float P[2 * 12 * PST];    // 64.5 KB
  __shared__ float Xb[12 * 240];       // 11.25 KB   (total 81.8 KB)
  const int tid = threadIdx.x;
  const int s0 = blockIdx.x * 12;
  const int kh = tid >> 8;             // wave-uniform
  const int g = tid & 255;
  const int jA = g, jB = 256 + g;

  for (int i = tid; i < 12 * 240; i += 512) Xb[i] = Xs[(size_t)s0 * 240 + i];
  for (int i = tid; i < 12 * 128; i += 512) h_s[i] = 0.0f;

  float4 wA[16], wB[16];
  {
    const float4* ra = (const float4*)(Whh + jA * 128 + kh * 64);
    const float4* rb = (const float4*)(Whh + jB * 128 + kh * 64);
#pragma unroll
    for (int q = 0; q < 16; q++) { wA[q] = ra[q]; wB[q] = rb[q]; }
  }
#pragma unroll
  for (int q = 0; q < 16; q++) {
    asm volatile("" : "+v"(wA[q].x), "+v"(wA[q].y), "+v"(wA[q].z), "+v"(wA[q].w));
    asm volatile("" : "+v"(wB[q].x), "+v"(wB[q].y), "+v"(wB[q].z), "+v"(wB[q].w));
  }

  const int jx = kh == 0 ? jA : jB;
  float wi[6];
#pragma unroll
  for (int f = 0; f < 6; f++) wi[f] = Wih[jx * 6 + f];
  const float bj = bih[jx] + bhh[jx];

  const int n = tid & 127, mg = tid >> 7;   // phase-2 role
  float c[3] = {0.0f, 0.0f, 0.0f};

  __syncthreads();

  for (int t = 0; t < 40; t++) {
    // ---- phase 1: gate partials ----
#pragma unroll 1
    for (int m = 0; m < 12; m++) {
      const float* xm = Xb + m * 240 + t * 6;
      float xp = bj;
      xp = fmaf(wi[0], xm[0], xp); xp = fmaf(wi[1], xm[1], xp);
      xp = fmaf(wi[2], xm[2], xp); xp = fmaf(wi[3], xm[3], xp);
      xp = fmaf(wi[4], xm[4], xp); xp = fmaf(wi[5], xm[5], xp);

      const float4* hp = (const float4*)(h_s + m * 128 + kh * 64);
      float aA0 = 0, aA1 = 0, aB0 = 0, aB1 = 0;
#pragma unroll
      for (int q = 0; q < 16; q += 2) {
        float4 h0 = hp[q], h1 = hp[q + 1];
        aA0 = fmaf(wA[q].x, h0.x, aA0); aA0 = fmaf(wA[q].y, h0.y, aA0);
        aA0 = fmaf(wA[q].z, h0.z, aA0); aA0 = fmaf(wA[q].w, h0.w, aA0);
        aB0 = fmaf(wB[q].x, h0.x, aB0); aB0 = fmaf(wB[q].y, h0.y, aB0);
        aB0 = fmaf(wB[q].z, h0.z, aB0); aB0 = fmaf(wB[q].w, h0.w, aB0);
        aA1 = fmaf(wA[q + 1].x, h1.x, aA1); aA1 = fmaf(wA[q + 1].y, h1.y, aA1);
        aA1 = fmaf(wA[q + 1].z, h1.z, aA1); aA1 = fmaf(wA[q + 1].w, h1.w, aA1);
        aB1 = fmaf(wB[q + 1].x, h1.x, aB1); aB1 = fmaf(wB[q + 1].y, h1.y, aB1);
        aB1 = fmaf(wB[q + 1].w, h1.w, aB1); aB1 = fmaf(wB[q + 1].z, h1.z, aB1);
      }
      float pA = aA0 + aA1 + (kh == 0 ? xp : 0.0f);
      float pB = aB0 + aB1 + (kh == 1 ? xp : 0.0f);
      P[(kh * 12 + m) * PST + jA] = pA;
      P[(kh * 12 + m) * PST + jB] = pB;
    }
    __syncthreads();

    // ---- phase 2: activations, c/h update (3 (m,n) tasks per thread) ----
#pragma unroll
    for (int r = 0; r < 3; r++) {
      const int m = mg + r * 4;
      const float* P0 = P + m * PST;
      const float* P1 = P + (12 + m) * PST;
      float gi = P0[n] + P1[n];
      float gf = P0[128 + n] + P1[128 + n];
      float gg = P0[256 + n] + P1[256 + n];
      float go = P0[384 + n] + P1[384 + n];
      c[r] = sigm(gf) * c[r] + sigm(gi) * tanhf(gg);
      float h = sigm(go) * tanhf(c[r]);
      h_s[m * 128 + n] = h;
      if (t >= 30) H10[((size_t)(s0 + m) * 10 + (t - 30)) * 128 + n] = h;
    }
    __syncthreads();
  }
}

// ---------------------------------------------------------------------------
// Kernel 2a: LayerNorm in-place (unchanged).
// ---------------------------------------------------------------------------
__global__ __launch_bounds__(256) void ln_kernel(
    float* __restrict__ H, const float* __restrict__ g,
    const float* __restrict__ b, int nrows)
{
  int row = blockIdx.x * 4 + (threadIdx.x >> 6);
  int lane = threadIdx.x & 63;
  if (row >= nrows) return;
  float* hr = H + (size_t)row * 128;
  float x0 = hr[lane], x1 = hr[lane + 64];
  float s = x0 + x1;
  for (int off = 32; off > 0; off >>= 1) s += __shfl_xor(s, off);
  float mean = s * (1.0f / 128.0f);
  float d0 = x0 - mean, d1 = x1 - mean;
  float v = d0 * d0 + d1 * d1;
  for (int off = 32; off > 0; off >>= 1) v += __shfl_xor(v, off);
  float rstd = 1.0f / sqrtf(v * (1.0f / 128.0f) + 1e-5f);
  hr[lane] = d0 * rstd * g[lane] + b[lane];
  hr[lane + 64] = d1 * rstd * g[lane + 64] + b[lane + 64];
}

// ---------------------------------------------------------------------------
// Kernel 2b: Out[r] = l2norm(In_row[r] @ W^T) (unchanged).
// ---------------------------------------------------------------------------
__global__ __launch_bounds__(256) void proj_kernel(
    const float* __restrict__ In, int inOff, int inStride, int nr,
    const float* __restrict__ W, float* __restrict__ Out)
{
  __shared__ float A_s[16 * 128];
  const int tid = threadIdx.x;
  const int r0 = blockIdx.x * 16;

  for (int i = tid; i < 16 * 32; i += 256) {
    int row = i >> 5, c = i & 31;
    int gr = r0 + row;
    float4 v = make_float4(0.f, 0.f, 0.f, 0.f);
    if (gr < nr)
      v = *(const float4*)(In + (size_t)inOff + (size_t)gr * inStride + c * 4);
    *(float4*)(A_s + row * 128 + c * 4) = v;
  }
  __syncthreads();

  const int j = tid & 127, rh = tid >> 7;
  const float* wrow = W + j * 128;
  float acc[8] = {0, 0, 0, 0, 0, 0, 0, 0};
  for (int kc = 0; kc < 32; kc++) {
    float4 wv4 = *(const float4*)(wrow + kc * 4);
#pragma unroll
    for (int i = 0; i < 8; i++) {
      float4 a4 = *(const float4*)(A_s + (rh * 8 + i) * 128 + kc * 4);
      acc[i] = fmaf(wv4.x, a4.x, acc[i]);
      acc[i] = fmaf(wv4.y, a4.y, acc[i]);
      acc[i] = fmaf(wv4.z, a4.z, acc[i]);
      acc[i] = fmaf(wv4.w, a4.w, acc[i]);
    }
  }
  __syncthreads();
#pragma unroll
  for (int i = 0; i < 8; i++) A_s[(rh * 8 + i) * 128 + j] = acc[i];
  __syncthreads();

  const int r = tid >> 4, qq = tid & 15;
  float ss = 0.0f;
#pragma unroll
  for (int i = 0; i < 8; i++) {
    float u = A_s[r * 128 + qq + i * 16];
    ss += u * u;
  }
  for (int off = 8; off > 0; off >>= 1) ss += __shfl_xor(ss, off);
  float scale = 1.0f / fmaxf(sqrtf(ss), 1e-12f);
  int gr = r0 + r;
  if (gr < nr) {
#pragma unroll
    for (int i = 0; i < 8; i++)
      Out[(size_t)gr * 128 + qq + i * 16] = A_s[r * 128 + qq + i * 16] * scale;
  }
}

// ---------------------------------------------------------------------------
// Kernel 2c-Q: fp32 -> (bf16 hi, bf16 lo) split, linear layout (Q only).
// ---------------------------------------------------------------------------
__global__ __launch_bounds__(256) void cvt_kernel(
    const float* __restrict__ src, unsigned short* __restrict__ hi,
    unsigned short* __restrict__ lo, int n4)
{
  int i = blockIdx.x * 256 + threadIdx.x;
  if (i >= n4) return;
  float4 f = ((const float4*)src)[i];
  ushort4 h, l;
  h.x = f2bf_rne(f.x); l.x = f2bf_rne(f.x - bf2f(h.x));
  h.y = f2bf_rne(f.y); l.y = f2bf_rne(f.y - bf2f(h.y));
  h.z = f2bf_rne(f.z); l.z = f2bf_rne(f.z - bf2f(h.z));
  h.w = f2bf_rne(f.w); l.w = f2bf_rne(f.w - bf2f(h.w));
  ((ushort4*)hi)[i] = h;
  ((ushort4*)lo)[i] = l;
}

// ---------------------------------------------------------------------------
// Kernel 2c-K: fp32 K -> blocked bf16 hi/lo for coalesced score loads.
// idx = tile*4096 + s*512 + half*256 + r*8 + e; col = s*16+half*8+e, r=row%32.
// ---------------------------------------------------------------------------
__global__ __launch_bounds__(256) void cvt_blockK(
    const float* __restrict__ Kn, unsigned short* __restrict__ hi,
    unsigned short* __restrict__ lo)
{
  const int tile = blockIdx.x;
  const int tid = threadIdx.x;
#pragma unroll
  for (int jj = 0; jj < 4; jj++) {
    int i = tid + jj * 256;
    int r = i >> 5;
    int c0 = (i & 31) * 4;
    int row = tile * 32 + r;
    if (row >= NCOLS) continue;
    float4 f = *(const float4*)(Kn + (size_t)row * 128 + c0);
    ushort4 h, l;
    h.x = f2bf_rne(f.x); l.x = f2bf_rne(f.x - bf2f(h.x));
    h.y = f2bf_rne(f.y); l.y = f2bf_rne(f.y - bf2f(h.y));
    h.z = f2bf_rne(f.z); l.z = f2bf_rne(f.z - bf2f(h.z));
    h.w = f2bf_rne(f.w); l.w = f2bf_rne(f.w - bf2f(h.w));
    int s = c0 >> 4, half = (c0 >> 3) & 1, e = c0 & 7;
    size_t idx = (size_t)tile * 4096 + s * 512 + half * 256 + r * 8 + e;
    *(ushort4*)(hi + idx) = h;
    *(ushort4*)(lo + idx) = l;
  }
}

// ---------------------------------------------------------------------------
// Kernel 3: MFMA score + per-chunk approx top-8, blocked-K coalesced loads.
// ---------------------------------------------------------------------------
__global__ __launch_bounds__(256, 3) void score_mfma(
    const unsigned short* __restrict__ Qh, const unsigned short* __restrict__ Ql,
    const unsigned short* __restrict__ Kh, const unsigned short* __restrict__ Kl,
    const int* __restrict__ tix, const float* __restrict__ log_temp,
    const float* __restrict__ lag_bias, float* __restrict__ part)
{
  __shared__ float lagS[16];
  __shared__ float M[256 * 16];
  const int tid = threadIdx.x;
  const int wv = tid >> 6, lane = tid & 63;
  const int half = lane >> 5, tcol = lane & 31;
  const int chunk = blockIdx.y;
  const int T0 = blockIdx.x * 32;
  const int tstart = chunk * TPC;
  const int tend = (tstart + TPC < KTILES) ? tstart + TPC : KTILES;

  if (tid < 10) lagS[tid] = lag_bias[tid];

  const int tgt = T0 + tcol;
  const int tgtc = tgt < S_N ? tgt : S_N - 1;
  const int myTix = tix[tgtc];
  const float invtemp =
      1.0f / fminf(fmaxf(expf(log_temp[0]), 0.1f), 11.313708499f);

  v8bf bh[8], bl[8];
  {
    const size_t qo = (size_t)myTix * 128 + half * 8;
#pragma unroll
    for (int s = 0; s < 8; s++) {
      bh[s] = *(const v8bf*)(Qh + qo + s * 16);
      bl[s] = *(const v8bf*)(Ql + qo + s * 16);
    }
  }
#pragma unroll
  for (int s = 0; s < 8; s++) {
    asm volatile("" : "+v"(bh[s]), "+v"(bl[s]));
  }

  float tv[8]; int ti[8];
#pragma unroll
  for (int q = 0; q < 8; q++) { tv[q] = -3e38f; ti[q] = 0x7fffffff; }

  __syncthreads();

  for (int it = 0; it < 15; it++) {
    const int tile = tstart + it * 4 + wv;
    const int tilec = tile < KTILES ? tile : KTILES - 1;
    const size_t ao = (size_t)tilec * 4096 + half * 256 + tcol * 8;

    v16f acc0, acc1;
#pragma unroll
    for (int q = 0; q < 16; q++) { acc0[q] = 0.0f; acc1[q] = 0.0f; }

#pragma unroll
    for (int s = 0; s < 8; s++) {
      v8bf ah = *(const v8bf*)(Kh + ao + s * 512);
      v8bf al = *(const v8bf*)(Kl + ao + s * 512);
      acc0 = __builtin_amdgcn_mfma_f32_32x32x16_bf16(ah, bh[s], acc0, 0, 0, 0);
      acc1 = __builtin_amdgcn_mfma_f32_32x32x16_bf16(ah, bl[s], acc1, 0, 0, 0);
      acc1 = __builtin_amdgcn_mfma_f32_32x32x16_bf16(al, bh[s], acc1, 0, 0, 0);
    }

    const int cb = tile * 32;
    const bool act = tile < tend;
#pragma unroll
    for (int reg = 0; reg < 16; reg++) {
      const int row = (reg & 3) + 8 * (reg >> 2) + 4 * half;
      const int col = cb + row;
      if (act && col < NCOLS) {
        const int s = col / 10;
        const int lag = col - s * 10;
        if (s != myTix) {
          float vsc = (acc0[reg] + acc1[reg]) * invtemp + lagS[lag];
          insS<8>(tv, ti, vsc, col);
        }
      }
    }
  }

  {
    float* my = M + tid * 16;
#pragma unroll
    for (int q = 0; q < 8; q++) {
      my[2 * q] = tv[q];
      my[2 * q + 1] = __int_as_float(ti[q]);
    }
  }
  __syncthreads();
  if (tid < 32 && T0 + tid < S_N) {
    float v[8]; int ix[8];
#pragma unroll
    for (int q = 0; q < 8; q++) { v[q] = -3e38f; ix[q] = 0x7fffffff; }
    for (int w = 0; w < 8; w++) {
      const float* src = M + (w * 32 + tid) * 16;
#pragma unroll
      for (int q = 0; q < 8; q++)
        insF<8>(v, ix, src[2 * q], __float_as_int(src[2 * q + 1]));
    }
    float* dst = part + ((size_t)(T0 + tid) * SCHUNK + chunk) * 16;
#pragma unroll
    for (int q = 0; q < 8; q++) {
      dst[2 * q] = v[q];
      dst[2 * q + 1] = __int_as_float(ix[q]);
    }
  }
}

// ---------------------------------------------------------------------------
// Kernel 4: merge chunks -> approx top-8, exact fp32 rescore -> exact top-5,
// softmax, gather z, MLP (unchanged).
// ---------------------------------------------------------------------------
__global__ __launch_bounds__(256) void final_kernel(
    const float* __restrict__ part, const float* __restrict__ Qn,
    const float* __restrict__ Kn, const int* __restrict__ tix,
    const float* __restrict__ log_temp, const float* __restrict__ lag_bias,
    const float* __restrict__ Xraw,
    const float* __restrict__ W1, const float* __restrict__ b1,
    const float* __restrict__ W2, const float* __restrict__ b2,
    const float* __restrict__ W3, const float* __restrict__ b3,
    float* __restrict__ out)
{
  __shared__ float W1s[64 * 12];
  __shared__ float W2s[32 * 64];
  __shared__ float b1s[64];
  __shared__ float b2s[32];
  __shared__ float W3s[32];
  const int tid = threadIdx.x;
  for (int i = tid; i < 768; i += 256) W1s[i] = W1[i];
  for (int i = tid; i < 2048; i += 256) W2s[i] = W2[i];
  if (tid < 64) b1s[tid] = b1[tid];
  if (tid < 32) { b2s[tid] = b2[tid]; W3s[tid] = W3[tid]; }
  __syncthreads();

  int t = blockIdx.x * 256 + tid;
  if (t >= S_N) return;

  float av[8]; int ai[8];
#pragma unroll
  for (int q = 0; q < 8; q++) { av[q] = -3e38f; ai[q] = 0x7fffffff; }
  const float* pp = part + (size_t)t * (SCHUNK * 16);
  for (int c = 0; c < SCHUNK * 8; c++)
    insF<8>(av, ai, pp[2 * c], __float_as_int(pp[2 * c + 1]));

  const float invtemp =
      1.0f / fminf(fmaxf(expf(log_temp[0]), 0.1f), 11.313708499f);
  const float* q = Qn + (size_t)tix[t] * 128;
  const float* kr[8];
#pragma unroll
  for (int j = 0; j < 8; j++) kr[j] = Kn + (size_t)ai[j] * 128;
  float d[8] = {0, 0, 0, 0, 0, 0, 0, 0};
  for (int kc = 0; kc < 32; kc++) {
    float4 q4 = ((const float4*)q)[kc];
#pragma unroll
    for (int j = 0; j < 8; j++) {
      float4 k4 = ((const float4*)kr[j])[kc];
      d[j] = fmaf(q4.x, k4.x, d[j]);
      d[j] = fmaf(q4.y, k4.y, d[j]);
      d[j] = fmaf(q4.z, k4.z, d[j]);
      d[j] = fmaf(q4.w, k4.w, d[j]);
    }
  }

  float v[5]; int ix[5];
#pragma unroll
  for (int qq = 0; qq < 5; qq++) { v[qq] = -3e38f; ix[qq] = 0x7fffffff; }
#pragma unroll
  for (int j = 0; j < 8; j++) {
    int c = ai[j];
    int s = c / 10;
    int lag = c - 10 * s;
    float ev = d[j] * invtemp + lag_bias[lag];
    insF<5>(v, ix, ev, c);
  }

  float e1 = expf(v[1] - v[0]), e2 = expf(v[2] - v[0]),
        e3 = expf(v[3] - v[0]), e4 = expf(v[4] - v[0]);
  float rs = 1.0f / (1.0f + e1 + e2 + e3 + e4);
  float w_[5] = {rs, e1 * rs, e2 * rs, e3 * rs, e4 * rs};

  float feat[12];
#pragma unroll
  for (int f = 0; f < 12; f++) feat[f] = 0.0f;
#pragma unroll
  for (int qq = 0; qq < 5; qq++) {
    int iq = ix[qq];
    int s = iq / 10;
    int l = iq - 10 * s;
    int pos = 29 + l;
    const float* zp = Xraw + (size_t)s * 240 + pos * 6;
#pragma unroll
    for (int f = 0; f < 6; f++) {
      float z = zp[f];
      feat[f] += w_[qq] * z;
      if (qq == 0) feat[6 + f] = z;
    }
  }

  float h1[64];
#pragma unroll 4
  for (int o = 0; o < 64; o++) {
    float acc = b1s[o];
    const float* wr = W1s + o * 12;
#pragma unroll
    for (int f = 0; f < 12; f++) acc = fmaf(wr[f], feat[f], acc);
    h1[o] = fmaxf(acc, 0.0f);
  }
  float rr = b3[0];
#pragma unroll 2
  for (int o = 0; o < 32; o++) {
    float acc = b2s[o];
    const float* wr = W2s + o * 64;
#pragma unroll 8
    for (int k = 0; k < 64; k++) acc = fmaf(wr[k], h1[k], acc);
    rr = fmaf(W3s[o], fmaxf(acc, 0.0f), rr);
  }
  out[t] = rr;
}

// ---------------------------------------------------------------------------
extern "C" void kernel_launch(void* const* d_in, const int* in_sizes, int n_in,
                              void* d_out, int out_size, void* d_ws,
                              size_t ws_size, hipStream_t stream) {
  const float* Xs   = (const float*)d_in[0];
  const float* Xraw = (const float*)d_in[1];
  const int*   tix  = (const int*)d_in[2];
  const float* Wih  = (const float*)d_in[3];
  const float* Whh  = (const float*)d_in[4];
  const float* bih  = (const float*)d_in[5];
  const float* bhh  = (const float*)d_in[6];
  const float* ln_g = (const float*)d_in[7];
  const float* ln_b = (const float*)d_in[8];
  const float* WQ   = (const float*)d_in[9];
  const float* WK   = (const float*)d_in[10];
  const float* log_temp = (const float*)d_in[11];
  const float* lag_bias = (const float*)d_in[12];
  const float* W1 = (const float*)d_in[13];
  const float* b1 = (const float*)d_in[14];
  const float* W2 = (const float*)d_in[15];
  const float* b2 = (const float*)d_in[16];
  const float* W3 = (const float*)d_in[17];
  const float* b3 = (const float*)d_in[18];
  float* outp = (float*)d_out;

  float* ws = (float*)d_ws;
  float* H10 = ws;                                          // [0, 3.84M)
  unsigned short* Khi = (unsigned short*)ws;                // overlays H10
  unsigned short* Klo = (unsigned short*)(ws + 1922000);
  float* Kn  = ws + 3850000;
  float* Qn  = ws + 7690000;
  unsigned short* Qhi = (unsigned short*)(ws + 8074000);
  unsigned short* Qlo = (unsigned short*)(ws + 8266000);
  float* part = ws + 8458000;

  lstm_kernel<<<250, 512, 0, stream>>>(Xs, Wih, Whh, bih, bhh, H10);
  ln_kernel<<<7500, 256, 0, stream>>>(H10, ln_g, ln_b, 30000);
  proj_kernel<<<1875, 256, 0, stream>>>(H10, 0, 128, 30000, WK, Kn);
  proj_kernel<<<188, 256, 0, stream>>>(H10, 9 * 128, 1280, 3000, WQ, Qn);
  cvt_blockK<<<KTILES, 256, 0, stream>>>(Kn, Khi, Klo);
  cvt_kernel<<<375, 256, 0, stream>>>(Qn, Qhi, Qlo, 96000);
  {
    dim3 grid(94, SCHUNK);
    score_mfma<<<grid, 256, 0, stream>>>(Qhi, Qlo, Khi, Klo, tix, log_temp,
                                         lag_bias, part);
  }
  final_kernel<<<12, 256, 0, stream>>>(part, Qn, Kn, tix, log_temp, lag_bias,
                                       Xraw, W1, b1, W2, b2, W3, b3, outp);
}

// Round 10
// 907.247 us; speedup vs baseline: 3.4620x; 3.4620x over previous
//
#include <hip/hip_runtime.h>
#include <math.h>

#define S_N 3000
#define NCOLS 30000
#define SCHUNK 16
#define KTILES 938      // ceil(30000/32)
#define TPC 59          // tiles per chunk (16*59 = 944 >= 938)

typedef __bf16 v8bf __attribute__((ext_vector_type(8)));
typedef float v16f __attribute__((ext_vector_type(16)));

__device__ __forceinline__ float sigm(float x) { return 1.0f / (1.0f + expf(-x)); }

__device__ __forceinline__ bool bet(float av, int ai, float bv, int bi) {
  return (av > bv) || (av == bv && ai < bi);
}

// streaming insert (candidates ascending by index): strict > == lax.top_k tie rule
template <int M>
__device__ __forceinline__ void insS(float (&v)[M], int (&ix)[M], float nv, int ni) {
  if (!(nv > v[M - 1])) return;
  bool b[M];
#pragma unroll
  for (int q = 0; q < M; q++) b[q] = nv > v[q];
#pragma unroll
  for (int q = M - 1; q > 0; q--) {
    v[q]  = b[q] ? (b[q - 1] ? v[q - 1] : nv) : v[q];
    ix[q] = b[q] ? (b[q - 1] ? ix[q - 1] : ni) : ix[q];
  }
  if (b[0]) { v[0] = nv; ix[0] = ni; }
}

// full comparator insert (value desc, index asc) for arbitrary-order merges
template <int M>
__device__ __forceinline__ void insF(float (&v)[M], int (&ix)[M], float nv, int ni) {
  if (!bet(nv, ni, v[M - 1], ix[M - 1])) return;
  bool b[M];
#pragma unroll
  for (int q = 0; q < M; q++) b[q] = bet(nv, ni, v[q], ix[q]);
#pragma unroll
  for (int q = M - 1; q > 0; q--) {
    v[q]  = b[q] ? (b[q - 1] ? v[q - 1] : nv) : v[q];
    ix[q] = b[q] ? (b[q - 1] ? ix[q - 1] : ni) : ix[q];
  }
  if (b[0]) { v[0] = nv; ix[0] = ni; }
}

__device__ __forceinline__ unsigned short f2bf_rne(float f) {
  unsigned int u = __float_as_uint(f);
  unsigned int r = (u + 0x7fffu + ((u >> 16) & 1u)) >> 16;
  return (unsigned short)r;
}
__device__ __forceinline__ float bf2f(unsigned short h) {
  return __uint_as_float(((unsigned int)h) << 16);
}

// ---------------------------------------------------------------------------
// Kernel 1: LSTM. 250 blocks x 1024 threads (R7 structure). Weights live in
// AGPRs (the allocator puts them there at the 128-reg cap regardless — R4-R9
// proved 128 is a hard ceiling here and large VGPR arrays shuttle or spill).
// NEW: phase 1 iterates k-chunks OUTER, sequences INNER: per chunk, 16
// explicit volatile v_accvgpr_read_b32 pull the weights into VGPRs ONCE,
// then 12 sequences x 16 FMA reuse them. Per-t VALU: 64 reads + 768 FMA
// (was 768 + 768 in R7 — compiler re-read per use). Volatile stops LICM
// from hoisting all 64 reads into permanently-live VGPRs (the spill trap).
// Per-sequence k-order is unchanged -> same summation order as R7.
// ---------------------------------------------------------------------------
__global__ __launch_bounds__(1024, 4) void lstm_kernel(
    const float* __restrict__ Xs, const float* __restrict__ Wih,
    const float* __restrict__ Whh, const float* __restrict__ bih,
    const float* __restrict__ bhh, float* __restrict__ H10)
{
  __shared__ float h_s[12 * 128];   // 6 KB
  __shared__ float P[2 * 12 * 512]; // 48 KB
  __shared__ float Xb[12 * 240];    // 11.25 KB  (65.25 KB -> 2 blocks/CU)
  const int tid = threadIdx.x;
  const int s0 = blockIdx.x * 12;

  for (int i = tid; i < 12 * 240; i += 1024) Xb[i] = Xs[(size_t)s0 * 240 + i];
  for (int i = tid; i < 12 * 128; i += 1024) h_s[i] = 0.0f;

  const int lane = tid & 63;
  const int wv = tid >> 6;
  const int j = (wv & 7) * 64 + lane;
  const int kh = wv >> 3;

  float4 w4[16];
  {
    const float4* wr = (const float4*)(Whh + j * 128 + kh * 64);
#pragma unroll
    for (int q = 0; q < 16; q++) w4[q] = wr[q];
  }
#pragma unroll
  for (int q = 0; q < 16; q++) {
    asm volatile("" : "+a"(w4[q].x), "+a"(w4[q].y), "+a"(w4[q].z),
                      "+a"(w4[q].w));
  }

  float wi0 = 0, wi1 = 0, wi2 = 0, wi3 = 0, wi4 = 0, wi5 = 0, bj = 0;
  if (kh == 0) {
    wi0 = Wih[j * 6 + 0]; wi1 = Wih[j * 6 + 1]; wi2 = Wih[j * 6 + 2];
    wi3 = Wih[j * 6 + 3]; wi4 = Wih[j * 6 + 4]; wi5 = Wih[j * 6 + 5];
    bj = bih[j] + bhh[j];
  }

  float c0 = 0.0f, c1 = 0.0f;
  const int p0m = tid >> 7;
  const int pn = tid & 127;

  __syncthreads();

  for (int t = 0; t < 40; t++) {
    // ---- phase 1: gate pre-activations (chunk-outer, sequence-inner) ----
    float acc[12];
    if (kh == 0) {
#pragma unroll
      for (int m = 0; m < 12; m++) {
        const float* xm = Xb + m * 240 + t * 6;
        float a = bj;
        a = fmaf(wi0, xm[0], a); a = fmaf(wi1, xm[1], a);
        a = fmaf(wi2, xm[2], a); a = fmaf(wi3, xm[3], a);
        a = fmaf(wi4, xm[4], a); a = fmaf(wi5, xm[5], a);
        acc[m] = a;
      }
    } else {
#pragma unroll
      for (int m = 0; m < 12; m++) acc[m] = 0.0f;
    }

#pragma unroll
    for (int chunk = 0; chunk < 4; chunk++) {
      float wc[16];
#pragma unroll
      for (int e = 0; e < 4; e++) {
        asm volatile("v_accvgpr_read_b32 %0, %1"
                     : "=v"(wc[e * 4 + 0]) : "a"(w4[chunk * 4 + e].x));
        asm volatile("v_accvgpr_read_b32 %0, %1"
                     : "=v"(wc[e * 4 + 1]) : "a"(w4[chunk * 4 + e].y));
        asm volatile("v_accvgpr_read_b32 %0, %1"
                     : "=v"(wc[e * 4 + 2]) : "a"(w4[chunk * 4 + e].z));
        asm volatile("v_accvgpr_read_b32 %0, %1"
                     : "=v"(wc[e * 4 + 3]) : "a"(w4[chunk * 4 + e].w));
      }
#pragma unroll
      for (int m = 0; m < 12; m++) {
        const float4* hp =
            (const float4*)(h_s + m * 128 + kh * 64 + chunk * 16);
        float4 h0 = hp[0], h1 = hp[1], h2 = hp[2], h3 = hp[3];
        float a = acc[m];
        a = fmaf(wc[0],  h0.x, a); a = fmaf(wc[1],  h0.y, a);
        a = fmaf(wc[2],  h0.z, a); a = fmaf(wc[3],  h0.w, a);
        a = fmaf(wc[4],  h1.x, a); a = fmaf(wc[5],  h1.y, a);
        a = fmaf(wc[6],  h1.z, a); a = fmaf(wc[7],  h1.w, a);
        a = fmaf(wc[8],  h2.x, a); a = fmaf(wc[9],  h2.y, a);
        a = fmaf(wc[10], h2.z, a); a = fmaf(wc[11], h2.w, a);
        a = fmaf(wc[12], h3.x, a); a = fmaf(wc[13], h3.y, a);
        a = fmaf(wc[14], h3.z, a); a = fmaf(wc[15], h3.w, a);
        acc[m] = a;
      }
    }
#pragma unroll
    for (int m = 0; m < 12; m++) P[(kh * 12 + m) * 512 + j] = acc[m];
    __syncthreads();

    // ---- phase 2: activations, c/h update ----
    {
      const int m = p0m, n = pn;
      const float* Pa = P + m * 512;
      const float* Pb = P + (12 + m) * 512;
      float gi = Pa[n] + Pb[n];
      float gf = Pa[n + 128] + Pb[n + 128];
      float gg = Pa[n + 256] + Pb[n + 256];
      float go = Pa[n + 384] + Pb[n + 384];
      c0 = sigm(gf) * c0 + sigm(gi) * tanhf(gg);
      float h = sigm(go) * tanhf(c0);
      h_s[m * 128 + n] = h;
      if (t >= 30) H10[((size_t)(s0 + m) * 10 + (t - 30)) * 128 + n] = h;
    }
    if (tid < 512) {
      const int m = 8 + p0m, n = pn;
      const float* Pa = P + m * 512;
      const float* Pb = P + (12 + m) * 512;
      float gi = Pa[n] + Pb[n];
      float gf = Pa[n + 128] + Pb[n + 128];
      float gg = Pa[n + 256] + Pb[n + 256];
      float go = Pa[n + 384] + Pb[n + 384];
      c1 = sigm(gf) * c1 + sigm(gi) * tanhf(gg);
      float h = sigm(go) * tanhf(c1);
      h_s[m * 128 + n] = h;
      if (t >= 30) H10[((size_t)(s0 + m) * 10 + (t - 30)) * 128 + n] = h;
    }
    __syncthreads();
  }
}

// ---------------------------------------------------------------------------
// Kernel 2a: LayerNorm in-place (unchanged).
// ---------------------------------------------------------------------------
__global__ __launch_bounds__(256) void ln_kernel(
    float* __restrict__ H, const float* __restrict__ g,
    const float* __restrict__ b, int nrows)
{
  int row = blockIdx.x * 4 + (threadIdx.x >> 6);
  int lane = threadIdx.x & 63;
  if (row >= nrows) return;
  float* hr = H + (size_t)row * 128;
  float x0 = hr[lane], x1 = hr[lane + 64];
  float s = x0 + x1;
  for (int off = 32; off > 0; off >>= 1) s += __shfl_xor(s, off);
  float mean = s * (1.0f / 128.0f);
  float d0 = x0 - mean, d1 = x1 - mean;
  float v = d0 * d0 + d1 * d1;
  for (int off = 32; off > 0; off >>= 1) v += __shfl_xor(v, off);
  float rstd = 1.0f / sqrtf(v * (1.0f / 128.0f) + 1e-5f);
  hr[lane] = d0 * rstd * g[lane] + b[lane];
  hr[lane + 64] = d1 * rstd * g[lane + 64] + b[lane + 64];
}

// ---------------------------------------------------------------------------
// Kernel 2b: Out[r] = l2norm(In_row[r] @ W^T) (unchanged).
// ---------------------------------------------------------------------------
__global__ __launch_bounds__(256) void proj_kernel(
    const float* __restrict__ In, int inOff, int inStride, int nr,
    const float* __restrict__ W, float* __restrict__ Out)
{
  __shared__ float A_s[16 * 128];
  const int tid = threadIdx.x;
  const int r0 = blockIdx.x * 16;

  for (int i = tid; i < 16 * 32; i += 256) {
    int row = i >> 5, c = i & 31;
    int gr = r0 + row;
    float4 v = make_float4(0.f, 0.f, 0.f, 0.f);
    if (gr < nr)
      v = *(const float4*)(In + (size_t)inOff + (size_t)gr * inStride + c * 4);
    *(float4*)(A_s + row * 128 + c * 4) = v;
  }
  __syncthreads();

  const int j = tid & 127, rh = tid >> 7;
  const float* wrow = W + j * 128;
  float acc[8] = {0, 0, 0, 0, 0, 0, 0, 0};
  for (int kc = 0; kc < 32; kc++) {
    float4 wv4 = *(const float4*)(wrow + kc * 4);
#pragma unroll
    for (int i = 0; i < 8; i++) {
      float4 a4 = *(const float4*)(A_s + (rh * 8 + i) * 128 + kc * 4);
      acc[i] = fmaf(wv4.x, a4.x, acc[i]);
      acc[i] = fmaf(wv4.y, a4.y, acc[i]);
      acc[i] = fmaf(wv4.z, a4.z, acc[i]);
      acc[i] = fmaf(wv4.w, a4.w, acc[i]);
    }
  }
  __syncthreads();
#pragma unroll
  for (int i = 0; i < 8; i++) A_s[(rh * 8 + i) * 128 + j] = acc[i];
  __syncthreads();

  const int r = tid >> 4, qq = tid & 15;
  float ss = 0.0f;
#pragma unroll
  for (int i = 0; i < 8; i++) {
    float u = A_s[r * 128 + qq + i * 16];
    ss += u * u;
  }
  for (int off = 8; off > 0; off >>= 1) ss += __shfl_xor(ss, off);
  float scale = 1.0f / fmaxf(sqrtf(ss), 1e-12f);
  int gr = r0 + r;
  if (gr < nr) {
#pragma unroll
    for (int i = 0; i < 8; i++)
      Out[(size_t)gr * 128 + qq + i * 16] = A_s[r * 128 + qq + i * 16] * scale;
  }
}

// ---------------------------------------------------------------------------
// Kernel 2c-Q: fp32 -> (bf16 hi, bf16 lo) split, linear layout (Q only).
// ---------------------------------------------------------------------------
__global__ __launch_bounds__(256) void cvt_kernel(
    const float* __restrict__ src, unsigned short* __restrict__ hi,
    unsigned short* __restrict__ lo, int n4)
{
  int i = blockIdx.x * 256 + threadIdx.x;
  if (i >= n4) return;
  float4 f = ((const float4*)src)[i];
  ushort4 h, l;
  h.x = f2bf_rne(f.x); l.x = f2bf_rne(f.x - bf2f(h.x));
  h.y = f2bf_rne(f.y); l.y = f2bf_rne(f.y - bf2f(h.y));
  h.z = f2bf_rne(f.z); l.z = f2bf_rne(f.z - bf2f(h.z));
  h.w = f2bf_rne(f.w); l.w = f2bf_rne(f.w - bf2f(h.w));
  ((ushort4*)hi)[i] = h;
  ((ushort4*)lo)[i] = l;
}

// ---------------------------------------------------------------------------
// Kernel 2c-K: fp32 K -> blocked bf16 hi/lo for coalesced score loads.
// idx = tile*4096 + s*512 + half*256 + r*8 + e; col = s*16+half*8+e, r=row%32.
// ---------------------------------------------------------------------------
__global__ __launch_bounds__(256) void cvt_blockK(
    const float* __restrict__ Kn, unsigned short* __restrict__ hi,
    unsigned short* __restrict__ lo)
{
  const int tile = blockIdx.x;
  const int tid = threadIdx.x;
#pragma unroll
  for (int jj = 0; jj < 4; jj++) {
    int i = tid + jj * 256;
    int r = i >> 5;
    int c0 = (i & 31) * 4;
    int row = tile * 32 + r;
    if (row >= NCOLS) continue;
    float4 f = *(const float4*)(Kn + (size_t)row * 128 + c0);
    ushort4 h, l;
    h.x = f2bf_rne(f.x); l.x = f2bf_rne(f.x - bf2f(h.x));
    h.y = f2bf_rne(f.y); l.y = f2bf_rne(f.y - bf2f(h.y));
    h.z = f2bf_rne(f.z); l.z = f2bf_rne(f.z - bf2f(h.z));
    h.w = f2bf_rne(f.w); l.w = f2bf_rne(f.w - bf2f(h.w));
    int s = c0 >> 4, half = (c0 >> 3) & 1, e = c0 & 7;
    size_t idx = (size_t)tile * 4096 + s * 512 + half * 256 + r * 8 + e;
    *(ushort4*)(hi + idx) = h;
    *(ushort4*)(lo + idx) = l;
  }
}

// ---------------------------------------------------------------------------
// Kernel 3: MFMA score + per-chunk approx top-8, blocked-K coalesced loads.
// ---------------------------------------------------------------------------
__global__ __launch_bounds__(256, 3) void score_mfma(
    const unsigned short* __restrict__ Qh, const unsigned short* __restrict__ Ql,
    const unsigned short* __restrict__ Kh, const unsigned short* __restrict__ Kl,
    const int* __restrict__ tix, const float* __restrict__ log_temp,
    const float* __restrict__ lag_bias, float* __restrict__ part)
{
  __shared__ float lagS[16];
  __shared__ float M[256 * 16];
  const int tid = threadIdx.x;
  const int wv = tid >> 6, lane = tid & 63;
  const int half = lane >> 5, tcol = lane & 31;
  const int chunk = blockIdx.y;
  const int T0 = blockIdx.x * 32;
  const int tstart = chunk * TPC;
  const int tend = (tstart + TPC < KTILES) ? tstart + TPC : KTILES;

  if (tid < 10) lagS[tid] = lag_bias[tid];

  const int tgt = T0 + tcol;
  const int tgtc = tgt < S_N ? tgt : S_N - 1;
  const int myTix = tix[tgtc];
  const float invtemp =
      1.0f / fminf(fmaxf(expf(log_temp[0]), 0.1f), 11.313708499f);

  v8bf bh[8], bl[8];
  {
    const size_t qo = (size_t)myTix * 128 + half * 8;
#pragma unroll
    for (int s = 0; s < 8; s++) {
      bh[s] = *(const v8bf*)(Qh + qo + s * 16);
      bl[s] = *(const v8bf*)(Ql + qo + s * 16);
    }
  }
#pragma unroll
  for (int s = 0; s < 8; s++) {
    asm volatile("" : "+v"(bh[s]), "+v"(bl[s]));
  }

  float tv[8]; int ti[8];
#pragma unroll
  for (int q = 0; q < 8; q++) { tv[q] = -3e38f; ti[q] = 0x7fffffff; }

  __syncthreads();

  for (int it = 0; it < 15; it++) {
    const int tile = tstart + it * 4 + wv;
    const int tilec = tile < KTILES ? tile : KTILES - 1;
    const size_t ao = (size_t)tilec * 4096 + half * 256 + tcol * 8;

    v16f acc0, acc1;
#pragma unroll
    for (int q = 0; q < 16; q++) { acc0[q] = 0.0f; acc1[q] = 0.0f; }

#pragma unroll
    for (int s = 0; s < 8; s++) {
      v8bf ah = *(const v8bf*)(Kh + ao + s * 512);
      v8bf al = *(const v8bf*)(Kl + ao + s * 512);
      acc0 = __builtin_amdgcn_mfma_f32_32x32x16_bf16(ah, bh[s], acc0, 0, 0, 0);
      acc1 = __builtin_amdgcn_mfma_f32_32x32x16_bf16(ah, bl[s], acc1, 0, 0, 0);
      acc1 = __builtin_amdgcn_mfma_f32_32x32x16_bf16(al, bh[s], acc1, 0, 0, 0);
    }

    const int cb = tile * 32;
    const bool act = tile < tend;
#pragma unroll
    for (int reg = 0; reg < 16; reg++) {
      const int row = (reg & 3) + 8 * (reg >> 2) + 4 * half;
      const int col = cb + row;
      if (act && col < NCOLS) {
        const int s = col / 10;
        const int lag = col - s * 10;
        if (s != myTix) {
          float vsc = (acc0[reg] + acc1[reg]) * invtemp + lagS[lag];
          insS<8>(tv, ti, vsc, col);
        }
      }
    }
  }

  {
    float* my = M + tid * 16;
#pragma unroll
    for (int q = 0; q < 8; q++) {
      my[2 * q] = tv[q];
      my[2 * q + 1] = __int_as_float(ti[q]);
    }
  }
  __syncthreads();
  if (tid < 32 && T0 + tid < S_N) {
    float v[8]; int ix[8];
#pragma unroll
    for (int q = 0; q < 8; q++) { v[q] = -3e38f; ix[q] = 0x7fffffff; }
    for (int w = 0; w < 8; w++) {
      const float* src = M + (w * 32 + tid) * 16;
#pragma unroll
      for (int q = 0; q < 8; q++)
        insF<8>(v, ix, src[2 * q], __float_as_int(src[2 * q + 1]));
    }
    float* dst = part + ((size_t)(T0 + tid) * SCHUNK + chunk) * 16;
#pragma unroll
    for (int q = 0; q < 8; q++) {
      dst[2 * q] = v[q];
      dst[2 * q + 1] = __int_as_float(ix[q]);
    }
  }
}

// ---------------------------------------------------------------------------
// Kernel 4: merge chunks -> approx top-8, exact fp32 rescore -> exact top-5,
// softmax, gather z, MLP (unchanged).
// ---------------------------------------------------------------------------
__global__ __launch_bounds__(256) void final_kernel(
    const float* __restrict__ part, const float* __restrict__ Qn,
    const float* __restrict__ Kn, const int* __restrict__ tix,
    const float* __restrict__ log_temp, const float* __restrict__ lag_bias,
    const float* __restrict__ Xraw,
    const float* __restrict__ W1, const float* __restrict__ b1,
    const float* __restrict__ W2, const float* __restrict__ b2,
    const float* __restrict__ W3, const float* __restrict__ b3,
    float* __restrict__ out)
{
  __shared__ float W1s[64 * 12];
  __shared__ float W2s[32 * 64];
  __shared__ float b1s[64];
  __shared__ float b2s[32];
  __shared__ float W3s[32];
  const int tid = threadIdx.x;
  for (int i = tid; i < 768; i += 256) W1s[i] = W1[i];
  for (int i = tid; i < 2048; i += 256) W2s[i] = W2[i];
  if (tid < 64) b1s[tid] = b1[tid];
  if (tid < 32) { b2s[tid] = b2[tid]; W3s[tid] = W3[tid]; }
  __syncthreads();

  int t = blockIdx.x * 256 + tid;
  if (t >= S_N) return;

  float av[8]; int ai[8];
#pragma unroll
  for (int q = 0; q < 8; q++) { av[q] = -3e38f; ai[q] = 0x7fffffff; }
  const float* pp = part + (size_t)t * (SCHUNK * 16);
  for (int c = 0; c < SCHUNK * 8; c++)
    insF<8>(av, ai, pp[2 * c], __float_as_int(pp[2 * c + 1]));

  const float invtemp =
      1.0f / fminf(fmaxf(expf(log_temp[0]), 0.1f), 11.313708499f);
  const float* q = Qn + (size_t)tix[t] * 128;
  const float* kr[8];
#pragma unroll
  for (int j = 0; j < 8; j++) kr[j] = Kn + (size_t)ai[j] * 128;
  float d[8] = {0, 0, 0, 0, 0, 0, 0, 0};
  for (int kc = 0; kc < 32; kc++) {
    float4 q4 = ((const float4*)q)[kc];
#pragma unroll
    for (int j = 0; j < 8; j++) {
      float4 k4 = ((const float4*)kr[j])[kc];
      d[j] = fmaf(q4.x, k4.x, d[j]);
      d[j] = fmaf(q4.y, k4.y, d[j]);
      d[j] = fmaf(q4.z, k4.z, d[j]);
      d[j] = fmaf(q4.w, k4.w, d[j]);
    }
  }

  float v[5]; int ix[5];
#pragma unroll
  for (int qq = 0; qq < 5; qq++) { v[qq] = -3e38f; ix[qq] = 0x7fffffff; }
#pragma unroll
  for (int j = 0; j < 8; j++) {
    int c = ai[j];
    int s = c / 10;
    int lag = c - 10 * s;
    float ev = d[j] * invtemp + lag_bias[lag];
    insF<5>(v, ix, ev, c);
  }

  float e1 = expf(v[1] - v[0]), e2 = expf(v[2] - v[0]),
        e3 = expf(v[3] - v[0]), e4 = expf(v[4] - v[0]);
  float rs = 1.0f / (1.0f + e1 + e2 + e3 + e4);
  float w_[5] = {rs, e1 * rs, e2 * rs, e3 * rs, e4 * rs};

  float feat[12];
#pragma unroll
  for (int f = 0; f < 12; f++) feat[f] = 0.0f;
#pragma unroll
  for (int qq = 0; qq < 5; qq++) {
    int iq = ix[qq];
    int s = iq / 10;
    int l = iq - 10 * s;
    int pos = 29 + l;
    const float* zp = Xraw + (size_t)s * 240 + pos * 6;
#pragma unroll
    for (int f = 0; f < 6; f++) {
      float z = zp[f];
      feat[f] += w_[qq] * z;
      if (qq == 0) feat[6 + f] = z;
    }
  }

  float h1[64];
#pragma unroll 4
  for (int o = 0; o < 64; o++) {
    float acc = b1s[o];
    const float* wr = W1s + o * 12;
#pragma unroll
    for (int f = 0; f < 12; f++) acc = fmaf(wr[f], feat[f], acc);
    h1[o] = fmaxf(acc, 0.0f);
  }
  float rr = b3[0];
#pragma unroll 2
  for (int o = 0; o < 32; o++) {
    float acc = b2s[o];
    const float* wr = W2s + o * 64;
#pragma unroll 8
    for (int k = 0; k < 64; k++) acc = fmaf(wr[k], h1[k], acc);
    rr = fmaf(W3s[o], fmaxf(acc, 0.0f), rr);
  }
  out[t] = rr;
}

// ---------------------------------------------------------------------------
extern "C" void kernel_launch(void* const* d_in, const int* in_sizes, int n_in,
                              void* d_out, int out_size, void* d_ws,
                              size_t ws_size, hipStream_t stream) {
  const float* Xs   = (const float*)d_in[0];
  const float* Xraw = (const float*)d_in[1];
  const int*   tix  = (const int*)d_in[2];
  const float* Wih  = (const float*)d_in[3];
  const float* Whh  = (const float*)d_in[4];
  const float* bih  = (const float*)d_in[5];
  const float* bhh  = (const float*)d_in[6];
  const float* ln_g = (const float*)d_in[7];
  const float* ln_b = (const float*)d_in[8];
  const float* WQ   = (const float*)d_in[9];
  const float* WK   = (const float*)d_in[10];
  const float* log_temp = (const float*)d_in[11];
  const float* lag_bias = (const float*)d_in[12];
  const float* W1 = (const float*)d_in[13];
  const float* b1 = (const float*)d_in[14];
  const float* W2 = (const float*)d_in[15];
  const float* b2 = (const float*)d_in[16];
  const float* W3 = (const float*)d_in[17];
  const float* b3 = (const float*)d_in[18];
  float* outp = (float*)d_out;

  float* ws = (float*)d_ws;
  float* H10 = ws;                                          // [0, 3.84M)
  unsigned short* Khi = (unsigned short*)ws;                // overlays H10
  unsigned short* Klo = (unsigned short*)(ws + 1922000);
  float* Kn  = ws + 3850000;
  float* Qn  = ws + 7690000;
  unsigned short* Qhi = (unsigned short*)(ws + 8074000);
  unsigned short* Qlo = (unsigned short*)(ws + 8266000);
  float* part = ws + 8458000;

  lstm_kernel<<<250, 1024, 0, stream>>>(Xs, Wih, Whh, bih, bhh, H10);
  ln_kernel<<<7500, 256, 0, stream>>>(H10, ln_g, ln_b, 30000);
  proj_kernel<<<1875, 256, 0, stream>>>(H10, 0, 128, 30000, WK, Kn);
  proj_kernel<<<188, 256, 0, stream>>>(H10, 9 * 128, 1280, 3000, WQ, Qn);
  cvt_blockK<<<KTILES, 256, 0, stream>>>(Kn, Khi, Klo);
  cvt_kernel<<<375, 256, 0, stream>>>(Qn, Qhi, Qlo, 96000);
  {
    dim3 grid(94, SCHUNK);
    score_mfma<<<grid, 256, 0, stream>>>(Qhi, Qlo, Khi, Klo, tix, log_temp,
                                         lag_bias, part);
  }
  final_kernel<<<12, 256, 0, stream>>>(part, Qn, Kn, tix, log_temp, lag_bias,
                                       Xraw, W1, b1, W2, b2, W3, b3, outp);
}

// Round 11
// 811.960 us; speedup vs baseline: 3.8683x; 1.1174x over previous
//
#include <hip/hip_runtime.h>
#include <math.h>

#define S_N 3000
#define NCOLS 30000
#define SCHUNK 16
#define KTILES 938      // ceil(30000/32)
#define TPC 59          // tiles per chunk (16*59 = 944 >= 938)
#define PST 17          // P row stride (floats): odd -> conflict-free

typedef __bf16 v8bf __attribute__((ext_vector_type(8)));
typedef float v16f __attribute__((ext_vector_type(16)));
typedef float v4f __attribute__((ext_vector_type(4)));

__device__ __forceinline__ float sigm(float x) { return 1.0f / (1.0f + expf(-x)); }

__device__ __forceinline__ bool bet(float av, int ai, float bv, int bi) {
  return (av > bv) || (av == bv && ai < bi);
}

// streaming insert (candidates ascending by index): strict > == lax.top_k tie rule
template <int M>
__device__ __forceinline__ void insS(float (&v)[M], int (&ix)[M], float nv, int ni) {
  if (!(nv > v[M - 1])) return;
  bool b[M];
#pragma unroll
  for (int q = 0; q < M; q++) b[q] = nv > v[q];
#pragma unroll
  for (int q = M - 1; q > 0; q--) {
    v[q]  = b[q] ? (b[q - 1] ? v[q - 1] : nv) : v[q];
    ix[q] = b[q] ? (b[q - 1] ? ix[q - 1] : ni) : ix[q];
  }
  if (b[0]) { v[0] = nv; ix[0] = ni; }
}

// full comparator insert (value desc, index asc) for arbitrary-order merges
template <int M>
__device__ __forceinline__ void insF(float (&v)[M], int (&ix)[M], float nv, int ni) {
  if (!bet(nv, ni, v[M - 1], ix[M - 1])) return;
  bool b[M];
#pragma unroll
  for (int q = 0; q < M; q++) b[q] = bet(nv, ni, v[q], ix[q]);
#pragma unroll
  for (int q = M - 1; q > 0; q--) {
    v[q]  = b[q] ? (b[q - 1] ? v[q - 1] : nv) : v[q];
    ix[q] = b[q] ? (b[q - 1] ? ix[q - 1] : ni) : ix[q];
  }
  if (b[0]) { v[0] = nv; ix[0] = ni; }
}

__device__ __forceinline__ unsigned short f2bf_rne(float f) {
  unsigned int u = __float_as_uint(f);
  unsigned int r = (u + 0x7fffu + ((u >> 16) & 1u)) >> 16;
  return (unsigned short)r;
}
__device__ __forceinline__ float bf2f(unsigned short h) {
  return __uint_as_float(((unsigned int)h) << 16);
}

// ---------------------------------------------------------------------------
// Kernel 0: Whh third-split (ll) in fragment order, streamed by lstm per t.
// idx = frag*512 + lane*8 + j; frag = w*8 + tau*2 + s (w = wave 0..15).
// ---------------------------------------------------------------------------
__global__ __launch_bounds__(256) void cvt_wll(
    const float* __restrict__ Whh, unsigned short* __restrict__ Wllf)
{
  int idx = blockIdx.x * 256 + threadIdx.x;
  if (idx >= 128 * 512) return;
  int f = idx >> 9;
  int lane = (idx >> 3) & 63;
  int j = idx & 7;
  int w = f >> 3, tau = (f >> 1) & 3, s = f & 1;
  int kh = w >> 3, g8 = w & 7;
  int gate = g8 * 64 + tau * 16 + (lane & 15);
  int k = kh * 64 + s * 32 + (lane >> 4) * 8 + j;
  float x = Whh[gate * 128 + k];
  unsigned short hi = f2bf_rne(x);
  float r1 = x - bf2f(hi);
  unsigned short lo = f2bf_rne(r1);
  float r2 = r1 - bf2f(lo);
  Wllf[idx] = f2bf_rne(r2);
}

// ---------------------------------------------------------------------------
// Kernel 1: LSTM via MFMA. 250 blocks x 1024 threads (16 waves), 1 block/CU
// (105 KB LDS). R7-R10 established phase-1 was LDS-broadcast-bound (192
// wave-uniform ds_read_b128/wave/t, 16 B useful each -> 370 us floor).
// Now the recurrent GEMM [12x128]@[128x512] runs on MFMA 16x16x32 with
// bf16 x3 splits (6 MFMAs per product: error ~2^-24, i.e. fp32-noise level,
// required because final top-5 ordering has no exact-rescore safety net
// against H perturbation). Wave (kh=wv>>3, g8=wv&7): 64 gates x K-half.
// Weights hi/lo resident (64 regs -> compiler auto-AGPRs them; MFMA reads
// AGPR operands natively, so no per-use shuttle). ll split streamed from
// L2 (prepacked by cvt_wll). x-part + bias stay exact fp32 in phase 2.
// LDS reads per wave per t: 6 lane-distributed b128 (was 192 broadcasts).
// ---------------------------------------------------------------------------
__global__ __launch_bounds__(1024, 4) void lstm_kernel(
    const float* __restrict__ Xs, const float* __restrict__ Wih,
    const float* __restrict__ Whh, const float* __restrict__ bih,
    const float* __restrict__ bhh, const unsigned short* __restrict__ Wllf,
    float* __restrict__ H10)
{
  __shared__ float P[2 * 512 * PST];                  // 69.6 KB
  __shared__ __align__(16) __bf16 Asp[3][4][64][8];   // 12 KB: h splits, A-frag layout
  __shared__ float Xb[12 * 240];                      // 11.25 KB
  __shared__ float2 WB2[14][128];                     // 14 KB: packed wih+bias

  const int tid = threadIdx.x;
  const int s0 = blockIdx.x * 12;
  const int lane = tid & 63;
  const int wv = tid >> 6;
  const int kh = wv >> 3;
  const int g8 = wv & 7;
  const int l15 = lane & 15, lq = lane >> 4;

  for (int i = tid; i < 12 * 240; i += 1024) Xb[i] = Xs[(size_t)s0 * 240 + i];
  for (int i = tid; i < 3 * 4 * 64 * 8; i += 1024)
    ((unsigned short*)Asp)[i] = 0;   // h0 = 0 (and zero pad rows)
  for (int i = tid; i < 14 * 128; i += 1024) {
    int q = i >> 7, n = i & 127;
    float vv[2];
#pragma unroll
    for (int e = 0; e < 2; e++) {
      int r = 2 * q + e;
      if (r < 24) {
        int gate = n + (r / 6) * 128;
        vv[e] = Wih[gate * 6 + r % 6];
      } else {
        int gate = n + (r - 24) * 128;
        vv[e] = bih[gate] + bhh[gate];
      }
    }
    WB2[q][n] = make_float2(vv[0], vv[1]);
  }

  // resident weight fragments hi/lo: B-layout (n=l15 -> gate, quad -> k+8*lq)
  v8bf whi[4][2], wlo[4][2];
#pragma unroll
  for (int tau = 0; tau < 4; tau++)
#pragma unroll
    for (int s = 0; s < 2; s++) {
      int gate = g8 * 64 + tau * 16 + l15;
      int k0 = kh * 64 + s * 32 + lq * 8;
      const float* wp = Whh + gate * 128 + k0;
      v8bf h8, l8;
#pragma unroll
      for (int j = 0; j < 8; j++) {
        float x = wp[j];
        __bf16 bh_ = (__bf16)x;
        float r1 = x - (float)bh_;
        __bf16 bl_ = (__bf16)r1;
        h8[j] = bh_;
        l8[j] = bl_;
      }
      whi[tau][s] = h8;
      wlo[tau][s] = l8;
    }

  const unsigned short* wllbase = Wllf + (size_t)(wv * 8) * 512 + lane * 8;

  float c0 = 0.0f, c1 = 0.0f;
  const int p2n = tid & 127;
  const int p2m = tid >> 7;   // 0..7

  __syncthreads();

#pragma unroll 1
  for (int t = 0; t < 40; t++) {
    // ---- phase 1: recurrent GEMM on MFMA ----
    v8bf ah[2], al[2], a3[2];
#pragma unroll
    for (int s = 0; s < 2; s++) {
      int ks = kh * 2 + s;
      ah[s] = *(const v8bf*)&Asp[0][ks][lane][0];
      al[s] = *(const v8bf*)&Asp[1][ks][lane][0];
      a3[s] = *(const v8bf*)&Asp[2][ks][lane][0];
    }
#pragma unroll
    for (int tau = 0; tau < 4; tau++) {
      v4f acc = {0.0f, 0.0f, 0.0f, 0.0f};
#pragma unroll
      for (int s = 0; s < 2; s++) {
        v8bf wll = *(const v8bf*)(wllbase + (tau * 2 + s) * 512);
        acc = __builtin_amdgcn_mfma_f32_16x16x32_bf16(ah[s], whi[tau][s], acc, 0, 0, 0);
        acc = __builtin_amdgcn_mfma_f32_16x16x32_bf16(ah[s], wlo[tau][s], acc, 0, 0, 0);
        acc = __builtin_amdgcn_mfma_f32_16x16x32_bf16(al[s], whi[tau][s], acc, 0, 0, 0);
        acc = __builtin_amdgcn_mfma_f32_16x16x32_bf16(al[s], wlo[tau][s], acc, 0, 0, 0);
        acc = __builtin_amdgcn_mfma_f32_16x16x32_bf16(ah[s], wll, acc, 0, 0, 0);
        acc = __builtin_amdgcn_mfma_f32_16x16x32_bf16(a3[s], whi[tau][s], acc, 0, 0, 0);
      }
      // D: row(m) = lq*4+reg, col(gate) = l15. Store m<12 (lq<3).
      if (lq < 3) {
        int gate = g8 * 64 + tau * 16 + l15;
        float* pp = P + kh * (512 * PST) + gate * PST + lq * 4;
#pragma unroll
        for (int reg = 0; reg < 4; reg++) pp[reg] = acc[reg];
      }
    }
    __syncthreads();

    // ---- phase 2: exact fp32 x-part + bias + activations + h-splits ----
#pragma unroll
    for (int task = 0; task < 2; task++) {
      if (task == 1 && tid >= 512) break;
      const int m = task == 0 ? p2m : 8 + p2m;
      const int n = p2n;
      float wb[28];
#pragma unroll
      for (int q = 0; q < 14; q++) {
        float2 v = WB2[q][n];
        wb[2 * q] = v.x;
        wb[2 * q + 1] = v.y;
      }
      const float* xm = Xb + m * 240 + t * 6;
      float xv[6];
#pragma unroll
      for (int f = 0; f < 6; f++) xv[f] = xm[f];
      float g4[4];
#pragma unroll
      for (int g = 0; g < 4; g++) {
        float a = wb[24 + g];
#pragma unroll
        for (int f = 0; f < 6; f++) a = fmaf(wb[g * 6 + f], xv[f], a);
        int gate = n + g * 128;
        a += P[gate * PST + m] + P[512 * PST + gate * PST + m];
        g4[g] = a;
      }
      float& c = task == 0 ? c0 : c1;
      c = sigm(g4[1]) * c + sigm(g4[0]) * tanhf(g4[2]);
      float h = sigm(g4[3]) * tanhf(c);
      if (t >= 30) H10[((size_t)(s0 + m) * 10 + (t - 30)) * 128 + n] = h;
      __bf16 hh = (__bf16)h;
      float r1 = h - (float)hh;
      __bf16 hl = (__bf16)r1;
      float r2 = r1 - (float)hl;
      __bf16 h3 = (__bf16)r2;
      int ks = n >> 5, li = m + 16 * ((n >> 3) & 3), j = n & 7;
      Asp[0][ks][li][j] = hh;
      Asp[1][ks][li][j] = hl;
      Asp[2][ks][li][j] = h3;
    }
    __syncthreads();
  }
}

// ---------------------------------------------------------------------------
// Kernel 2a: LayerNorm in-place (unchanged).
// ---------------------------------------------------------------------------
__global__ __launch_bounds__(256) void ln_kernel(
    float* __restrict__ H, const float* __restrict__ g,
    const float* __restrict__ b, int nrows)
{
  int row = blockIdx.x * 4 + (threadIdx.x >> 6);
  int lane = threadIdx.x & 63;
  if (row >= nrows) return;
  float* hr = H + (size_t)row * 128;
  float x0 = hr[lane], x1 = hr[lane + 64];
  float s = x0 + x1;
  for (int off = 32; off > 0; off >>= 1) s += __shfl_xor(s, off);
  float mean = s * (1.0f / 128.0f);
  float d0 = x0 - mean, d1 = x1 - mean;
  float v = d0 * d0 + d1 * d1;
  for (int off = 32; off > 0; off >>= 1) v += __shfl_xor(v, off);
  float rstd = 1.0f / sqrtf(v * (1.0f / 128.0f) + 1e-5f);
  hr[lane] = d0 * rstd * g[lane] + b[lane];
  hr[lane + 64] = d1 * rstd * g[lane + 64] + b[lane + 64];
}

// ---------------------------------------------------------------------------
// Kernel 2b: Out[r] = l2norm(In_row[r] @ W^T) (unchanged).
// ---------------------------------------------------------------------------
__global__ __launch_bounds__(256) void proj_kernel(
    const float* __restrict__ In, int inOff, int inStride, int nr,
    const float* __restrict__ W, float* __restrict__ Out)
{
  __shared__ float A_s[16 * 128];
  const int tid = threadIdx.x;
  const int r0 = blockIdx.x * 16;

  for (int i = tid; i < 16 * 32; i += 256) {
    int row = i >> 5, c = i & 31;
    int gr = r0 + row;
    float4 v = make_float4(0.f, 0.f, 0.f, 0.f);
    if (gr < nr)
      v = *(const float4*)(In + (size_t)inOff + (size_t)gr * inStride + c * 4);
    *(float4*)(A_s + row * 128 + c * 4) = v;
  }
  __syncthreads();

  const int j = tid & 127, rh = tid >> 7;
  const float* wrow = W + j * 128;
  float acc[8] = {0, 0, 0, 0, 0, 0, 0, 0};
  for (int kc = 0; kc < 32; kc++) {
    float4 wv4 = *(const float4*)(wrow + kc * 4);
#pragma unroll
    for (int i = 0; i < 8; i++) {
      float4 a4 = *(const float4*)(A_s + (rh * 8 + i) * 128 + kc * 4);
      acc[i] = fmaf(wv4.x, a4.x, acc[i]);
      acc[i] = fmaf(wv4.y, a4.y, acc[i]);
      acc[i] = fmaf(wv4.z, a4.z, acc[i]);
      acc[i] = fmaf(wv4.w, a4.w, acc[i]);
    }
  }
  __syncthreads();
#pragma unroll
  for (int i = 0; i < 8; i++) A_s[(rh * 8 + i) * 128 + j] = acc[i];
  __syncthreads();

  const int r = tid >> 4, qq = tid & 15;
  float ss = 0.0f;
#pragma unroll
  for (int i = 0; i < 8; i++) {
    float u = A_s[r * 128 + qq + i * 16];
    ss += u * u;
  }
  for (int off = 8; off > 0; off >>= 1) ss += __shfl_xor(ss, off);
  float scale = 1.0f / fmaxf(sqrtf(ss), 1e-12f);
  int gr = r0 + r;
  if (gr < nr) {
#pragma unroll
    for (int i = 0; i < 8; i++)
      Out[(size_t)gr * 128 + qq + i * 16] = A_s[r * 128 + qq + i * 16] * scale;
  }
}

// ---------------------------------------------------------------------------
// Kernel 2c-Q: fp32 -> (bf16 hi, bf16 lo) split, linear layout (Q only).
// ---------------------------------------------------------------------------
__global__ __launch_bounds__(256) void cvt_kernel(
    const float* __restrict__ src, unsigned short* __restrict__ hi,
    unsigned short* __restrict__ lo, int n4)
{
  int i = blockIdx.x * 256 + threadIdx.x;
  if (i >= n4) return;
  float4 f = ((const float4*)src)[i];
  ushort4 h, l;
  h.x = f2bf_rne(f.x); l.x = f2bf_rne(f.x - bf2f(h.x));
  h.y = f2bf_rne(f.y); l.y = f2bf_rne(f.y - bf2f(h.y));
  h.z = f2bf_rne(f.z); l.z = f2bf_rne(f.z - bf2f(h.z));
  h.w = f2bf_rne(f.w); l.w = f2bf_rne(f.w - bf2f(h.w));
  ((ushort4*)hi)[i] = h;
  ((ushort4*)lo)[i] = l;
}

// ---------------------------------------------------------------------------
// Kernel 2c-K: fp32 K -> blocked bf16 hi/lo for coalesced score loads.
// idx = tile*4096 + s*512 + half*256 + r*8 + e; col = s*16+half*8+e, r=row%32.
// ---------------------------------------------------------------------------
__global__ __launch_bounds__(256) void cvt_blockK(
    const float* __restrict__ Kn, unsigned short* __restrict__ hi,
    unsigned short* __restrict__ lo)
{
  const int tile = blockIdx.x;
  const int tid = threadIdx.x;
#pragma unroll
  for (int jj = 0; jj < 4; jj++) {
    int i = tid + jj * 256;
    int r = i >> 5;
    int c0 = (i & 31) * 4;
    int row = tile * 32 + r;
    if (row >= NCOLS) continue;
    float4 f = *(const float4*)(Kn + (size_t)row * 128 + c0);
    ushort4 h, l;
    h.x = f2bf_rne(f.x); l.x = f2bf_rne(f.x - bf2f(h.x));
    h.y = f2bf_rne(f.y); l.y = f2bf_rne(f.y - bf2f(h.y));
    h.z = f2bf_rne(f.z); l.z = f2bf_rne(f.z - bf2f(h.z));
    h.w = f2bf_rne(f.w); l.w = f2bf_rne(f.w - bf2f(h.w));
    int s = c0 >> 4, half = (c0 >> 3) & 1, e = c0 & 7;
    size_t idx = (size_t)tile * 4096 + s * 512 + half * 256 + r * 8 + e;
    *(ushort4*)(hi + idx) = h;
    *(ushort4*)(lo + idx) = l;
  }
}

// ---------------------------------------------------------------------------
// Kernel 3: MFMA score + per-chunk approx top-8, blocked-K coalesced loads
// (unchanged from R10).
// ---------------------------------------------------------------------------
__global__ __launch_bounds__(256, 3) void score_mfma(
    const unsigned short* __restrict__ Qh, const unsigned short* __restrict__ Ql,
    const unsigned short* __restrict__ Kh, const unsigned short* __restrict__ Kl,
    const int* __restrict__ tix, const float* __restrict__ log_temp,
    const float* __restrict__ lag_bias, float* __restrict__ part)
{
  __shared__ float lagS[16];
  __shared__ float M[256 * 16];
  const int tid = threadIdx.x;
  const int wv = tid >> 6, lane = tid & 63;
  const int half = lane >> 5, tcol = lane & 31;
  const int chunk = blockIdx.y;
  const int T0 = blockIdx.x * 32;
  const int tstart = chunk * TPC;
  const int tend = (tstart + TPC < KTILES) ? tstart + TPC : KTILES;

  if (tid < 10) lagS[tid] = lag_bias[tid];

  const int tgt = T0 + tcol;
  const int tgtc = tgt < S_N ? tgt : S_N - 1;
  const int myTix = tix[tgtc];
  const float invtemp =
      1.0f / fminf(fmaxf(expf(log_temp[0]), 0.1f), 11.313708499f);

  v8bf bh[8], bl[8];
  {
    const size_t qo = (size_t)myTix * 128 + half * 8;
#pragma unroll
    for (int s = 0; s < 8; s++) {
      bh[s] = *(const v8bf*)(Qh + qo + s * 16);
      bl[s] = *(const v8bf*)(Ql + qo + s * 16);
    }
  }
#pragma unroll
  for (int s = 0; s < 8; s++) {
    asm volatile("" : "+v"(bh[s]), "+v"(bl[s]));
  }

  float tv[8]; int ti[8];
#pragma unroll
  for (int q = 0; q < 8; q++) { tv[q] = -3e38f; ti[q] = 0x7fffffff; }

  __syncthreads();

  for (int it = 0; it < 15; it++) {
    const int tile = tstart + it * 4 + wv;
    const int tilec = tile < KTILES ? tile : KTILES - 1;
    const size_t ao = (size_t)tilec * 4096 + half * 256 + tcol * 8;

    v16f acc0, acc1;
#pragma unroll
    for (int q = 0; q < 16; q++) { acc0[q] = 0.0f; acc1[q] = 0.0f; }

#pragma unroll
    for (int s = 0; s < 8; s++) {
      v8bf ah = *(const v8bf*)(Kh + ao + s * 512);
      v8bf al = *(const v8bf*)(Kl + ao + s * 512);
      acc0 = __builtin_amdgcn_mfma_f32_32x32x16_bf16(ah, bh[s], acc0, 0, 0, 0);
      acc1 = __builtin_amdgcn_mfma_f32_32x32x16_bf16(ah, bl[s], acc1, 0, 0, 0);
      acc1 = __builtin_amdgcn_mfma_f32_32x32x16_bf16(al, bh[s], acc1, 0, 0, 0);
    }

    const int cb = tile * 32;
    const bool act = tile < tend;
#pragma unroll
    for (int reg = 0; reg < 16; reg++) {
      const int row = (reg & 3) + 8 * (reg >> 2) + 4 * half;
      const int col = cb + row;
      if (act && col < NCOLS) {
        const int s = col / 10;
        const int lag = col - s * 10;
        if (s != myTix) {
          float vsc = (acc0[reg] + acc1[reg]) * invtemp + lagS[lag];
          insS<8>(tv, ti, vsc, col);
        }
      }
    }
  }

  {
    float* my = M + tid * 16;
#pragma unroll
    for (int q = 0; q < 8; q++) {
      my[2 * q] = tv[q];
      my[2 * q + 1] = __int_as_float(ti[q]);
    }
  }
  __syncthreads();
  if (tid < 32 && T0 + tid < S_N) {
    float v[8]; int ix[8];
#pragma unroll
    for (int q = 0; q < 8; q++) { v[q] = -3e38f; ix[q] = 0x7fffffff; }
    for (int w = 0; w < 8; w++) {
      const float* src = M + (w * 32 + tid) * 16;
#pragma unroll
      for (int q = 0; q < 8; q++)
        insF<8>(v, ix, src[2 * q], __float_as_int(src[2 * q + 1]));
    }
    float* dst = part + ((size_t)(T0 + tid) * SCHUNK + chunk) * 16;
#pragma unroll
    for (int q = 0; q < 8; q++) {
      dst[2 * q] = v[q];
      dst[2 * q + 1] = __int_as_float(ix[q]);
    }
  }
}

// ---------------------------------------------------------------------------
// Kernel 4: merge chunks -> approx top-8, exact fp32 rescore -> exact top-5,
// softmax, gather z, MLP (unchanged).
// ---------------------------------------------------------------------------
__global__ __launch_bounds__(256) void final_kernel(
    const float* __restrict__ part, const float* __restrict__ Qn,
    const float* __restrict__ Kn, const int* __restrict__ tix,
    const float* __restrict__ log_temp, const float* __restrict__ lag_bias,
    const float* __restrict__ Xraw,
    const float* __restrict__ W1, const float* __restrict__ b1,
    const float* __restrict__ W2, const float* __restrict__ b2,
    const float* __restrict__ W3, const float* __restrict__ b3,
    float* __restrict__ out)
{
  __shared__ float W1s[64 * 12];
  __shared__ float W2s[32 * 64];
  __shared__ float b1s[64];
  __shared__ float b2s[32];
  __shared__ float W3s[32];
  const int tid = threadIdx.x;
  for (int i = tid; i < 768; i += 256) W1s[i] = W1[i];
  for (int i = tid; i < 2048; i += 256) W2s[i] = W2[i];
  if (tid < 64) b1s[tid] = b1[tid];
  if (tid < 32) { b2s[tid] = b2[tid]; W3s[tid] = W3[tid]; }
  __syncthreads();

  int t = blockIdx.x * 256 + tid;
  if (t >= S_N) return;

  float av[8]; int ai[8];
#pragma unroll
  for (int q = 0; q < 8; q++) { av[q] = -3e38f; ai[q] = 0x7fffffff; }
  const float* pp = part + (size_t)t * (SCHUNK * 16);
  for (int c = 0; c < SCHUNK * 8; c++)
    insF<8>(av, ai, pp[2 * c], __float_as_int(pp[2 * c + 1]));

  const float invtemp =
      1.0f / fminf(fmaxf(expf(log_temp[0]), 0.1f), 11.313708499f);
  const float* q = Qn + (size_t)tix[t] * 128;
  const float* kr[8];
#pragma unroll
  for (int j = 0; j < 8; j++) kr[j] = Kn + (size_t)ai[j] * 128;
  float d[8] = {0, 0, 0, 0, 0, 0, 0, 0};
  for (int kc = 0; kc < 32; kc++) {
    float4 q4 = ((const float4*)q)[kc];
#pragma unroll
    for (int j = 0; j < 8; j++) {
      float4 k4 = ((const float4*)kr[j])[kc];
      d[j] = fmaf(q4.x, k4.x, d[j]);
      d[j] = fmaf(q4.y, k4.y, d[j]);
      d[j] = fmaf(q4.z, k4.z, d[j]);
      d[j] = fmaf(q4.w, k4.w, d[j]);
    }
  }

  float v[5]; int ix[5];
#pragma unroll
  for (int qq = 0; qq < 5; qq++) { v[qq] = -3e38f; ix[qq] = 0x7fffffff; }
#pragma unroll
  for (int j = 0; j < 8; j++) {
    int c = ai[j];
    int s = c / 10;
    int lag = c - 10 * s;
    float ev = d[j] * invtemp + lag_bias[lag];
    insF<5>(v, ix, ev, c);
  }

  float e1 = expf(v[1] - v[0]), e2 = expf(v[2] - v[0]),
        e3 = expf(v[3] - v[0]), e4 = expf(v[4] - v[0]);
  float rs = 1.0f / (1.0f + e1 + e2 + e3 + e4);
  float w_[5] = {rs, e1 * rs, e2 * rs, e3 * rs, e4 * rs};

  float feat[12];
#pragma unroll
  for (int f = 0; f < 12; f++) feat[f] = 0.0f;
#pragma unroll
  for (int qq = 0; qq < 5; qq++) {
    int iq = ix[qq];
    int s = iq / 10;
    int l = iq - 10 * s;
    int pos = 29 + l;
    const float* zp = Xraw + (size_t)s * 240 + pos * 6;
#pragma unroll
    for (int f = 0; f < 6; f++) {
      float z = zp[f];
      feat[f] += w_[qq] * z;
      if (qq == 0) feat[6 + f] = z;
    }
  }

  float h1[64];
#pragma unroll 4
  for (int o = 0; o < 64; o++) {
    float acc = b1s[o];
    const float* wr = W1s + o * 12;
#pragma unroll
    for (int f = 0; f < 12; f++) acc = fmaf(wr[f], feat[f], acc);
    h1[o] = fmaxf(acc, 0.0f);
  }
  float rr = b3[0];
#pragma unroll 2
  for (int o = 0; o < 32; o++) {
    float acc = b2s[o];
    const float* wr = W2s + o * 64;
#pragma unroll 8
    for (int k = 0; k < 64; k++) acc = fmaf(wr[k], h1[k], acc);
    rr = fmaf(W3s[o], fmaxf(acc, 0.0f), rr);
  }
  out[t] = rr;
}

// ---------------------------------------------------------------------------
extern "C" void kernel_launch(void* const* d_in, const int* in_sizes, int n_in,
                              void* d_out, int out_size, void* d_ws,
                              size_t ws_size, hipStream_t stream) {
  const float* Xs   = (const float*)d_in[0];
  const float* Xraw = (const float*)d_in[1];
  const int*   tix  = (const int*)d_in[2];
  const float* Wih  = (const float*)d_in[3];
  const float* Whh  = (const float*)d_in[4];
  const float* bih  = (const float*)d_in[5];
  const float* bhh  = (const float*)d_in[6];
  const float* ln_g = (const float*)d_in[7];
  const float* ln_b = (const float*)d_in[8];
  const float* WQ   = (const float*)d_in[9];
  const float* WK   = (const float*)d_in[10];
  const float* log_temp = (const float*)d_in[11];
  const float* lag_bias = (const float*)d_in[12];
  const float* W1 = (const float*)d_in[13];
  const float* b1 = (const float*)d_in[14];
  const float* W2 = (const float*)d_in[15];
  const float* b2 = (const float*)d_in[16];
  const float* W3 = (const float*)d_in[17];
  const float* b3 = (const float*)d_in[18];
  float* outp = (float*)d_out;

  float* ws = (float*)d_ws;
  float* H10 = ws;                                          // [0, 3.84M)
  unsigned short* Khi = (unsigned short*)ws;                // overlays H10
  unsigned short* Klo = (unsigned short*)(ws + 1922000);
  float* Kn  = ws + 3850000;
  float* Qn  = ws + 7690000;
  unsigned short* Qhi = (unsigned short*)(ws + 8074000);
  unsigned short* Qlo = (unsigned short*)(ws + 8266000);
  float* part = ws + 8458000;                               // 768000 fl
  unsigned short* Wllf = (unsigned short*)(ws + 9226000);   // 65536 us

  cvt_wll<<<256, 256, 0, stream>>>(Whh, Wllf);
  lstm_kernel<<<250, 1024, 0, stream>>>(Xs, Wih, Whh, bih, bhh, Wllf, H10);
  ln_kernel<<<7500, 256, 0, stream>>>(H10, ln_g, ln_b, 30000);
  proj_kernel<<<1875, 256, 0, stream>>>(H10, 0, 128, 30000, WK, Kn);
  proj_kernel<<<188, 256, 0, stream>>>(H10, 9 * 128, 1280, 3000, WQ, Qn);
  cvt_blockK<<<KTILES, 256, 0, stream>>>(Kn, Khi, Klo);
  cvt_kernel<<<375, 256, 0, stream>>>(Qn, Qhi, Qlo, 96000);
  {
    dim3 grid(94, SCHUNK);
    score_mfma<<<grid, 256, 0, stream>>>(Qhi, Qlo, Khi, Klo, tix, log_temp,
                                         lag_bias, part);
  }
  final_kernel<<<12, 256, 0, stream>>>(part, Qn, Kn, tix, log_temp, lag_bias,
                                       Xraw, W1, b1, W2, b2, W3, b3, outp);
}